// Round 6
// baseline (128.188 us; speedup 1.0000x reference)
//
#include <hip/hip_runtime.h>
#include <math.h>

#define NM 16
#define VMAX 1080
#define UMAX 1920
#define WPR (UMAX/32)          // 60 words per row (240 B, 16B-aligned)
#define FGN 2048
#define BGN 2048
#define NPT (FGN+BGN)          // 4096
#define PTS_FLOATS (NM*NPT*8)  // 524288
#define DET_BLOCKS 64
#define DET_WORDS (VMAX*UMAX/4)   // scan mask 0 as-if-u8: 518400 words (2 MB)

// ---- workspace layout (bytes) ----
#define OFF_FLAG    0              // 64 ints: per-detect-block dtype code
#define OFF_INFO    256
#define OFF_BITMAP  4096
#define OFF_ROWCNT  (OFF_BITMAP + NM*VMAX*WPR*4)
#define OFF_RUSUM   (OFF_ROWCNT + NM*VMAX*4)
#define OFF_RUMIN   (OFF_RUSUM  + NM*VMAX*4)
#define OFF_RUMAX   (OFF_RUMIN  + NM*VMAX*4)
#define OFF_PF      (OFF_RUMAX  + NM*VMAX*4)
#define OFF_PB      (OFF_PF     + NM*(VMAX+1)*4)
// end ~4.5 MB

struct MaskInfo {
  int v0e, v1e, u0e, u1e, cnt_fg, cnt_bg;
  float cntf, vc, uc;
  int v0m, v1m;
  int pad[5];
};

// bits of word index widx that fall in bit-range [a, b)
__device__ inline unsigned int rangemask(int widx, int a, int b) {
  int lo = widx << 5, hi = lo + 32;
  if (b <= lo || a >= hi) return 0u;
  unsigned int m = 0xFFFFFFFFu;
  if (a > lo) m &= 0xFFFFFFFFu << (a - lo);
  if (b < hi) m &= (1u << (b - lo)) - 1u;
  return m;
}

// u8-evidence: any byte above byte0 nonzero, and the word cannot be a lone
// f32 1.0f. (u8 masks of 0/1 bytes can never form 0x3F800000.)
__device__ inline int u8_evidence(unsigned int x) {
  return (x & 0xFFFFFF00u) != 0u && x != 0x3F800000u;
}

// 64 blocks; block b scans its strided share of mask 0 (as-if-u8 = 2MB) and
// plain-stores code to flag[b]: 2 = u8 evidence, 3 = none. No atomics, no
// zero-init needed; deterministic regardless of prior flag contents.
__global__ __launch_bounds__(256) void k_detect(const uint4* w4, int* flag) {
  __shared__ int sev;
  if (threadIdx.x == 0) sev = 0;
  __syncthreads();
  int local = 0;
  const int nq = DET_WORDS / 4;  // 129600 uint4s
  for (int i = blockIdx.x * 256 + threadIdx.x; i < nq; i += DET_BLOCKS * 256) {
    uint4 x = w4[i];
    local |= u8_evidence(x.x) | u8_evidence(x.y) | u8_evidence(x.z) | u8_evidence(x.w);
  }
  if (__any(local)) { if ((threadIdx.x & 63) == 0) atomicOr(&sev, 1); }
  __syncthreads();
  if (threadIdx.x == 0) flag[blockIdx.x] = sev ? 2 : 3;
}

__device__ inline unsigned int bits4(unsigned int x) {  // 4 bytes -> 4 bits
  unsigned int r = 0;
  r |= (x & 0x000000FFu) ? 1u : 0u;
  r |= (x & 0x0000FF00u) ? 2u : 0u;
  r |= (x & 0x00FF0000u) ? 4u : 0u;
  r |= (x & 0xFF000000u) ? 8u : 0u;
  return r;
}
__device__ inline unsigned int bits16(uint4 q) {        // 16 bytes -> 16 bits
  return bits4(q.x) | (bits4(q.y) << 4) | (bits4(q.z) << 8) | (bits4(q.w) << 12);
}

// 4 waves per block, one wave per (mask,row); lane w owns bitmap word w
__global__ __launch_bounds__(256) void k_rows(const void* masks, char* ws) {
  const int R = blockIdx.x * 4 + (threadIdx.x >> 6);  // global row 0..NM*VMAX-1
  const int lane = threadIdx.x & 63;
  const int n = R / VMAX, v = R % VMAX;
  // mode: wave-reduce min over the 64 detect codes (one coalesced load)
  int code = ((const int*)(ws + OFF_FLAG))[lane];
  for (int off = 32; off > 0; off >>= 1) code = min(code, __shfl_xor(code, off));
  const bool is_u8 = (code == 2);
  const long long base = (long long)n * VMAX * UMAX + (long long)v * UMAX;  // element idx
  const int w = lane;
  unsigned int word = 0;
  if (w < WPR) {
    if (is_u8) {                // u8: 32 bytes = 2 x uint4
      const uint4* p = (const uint4*)((const unsigned char*)masks + base) + w * 2;
      uint4 a = p[0], b = p[1];
      word = bits16(a) | (bits16(b) << 16);
    } else {                    // i32 / f32: 32 dwords = 8 x uint4, nonzero == true
      const uint4* p = (const uint4*)((const unsigned int*)masks + base) + w * 8;
      #pragma unroll
      for (int t = 0; t < 8; t++) {
        uint4 x = p[t];
        unsigned int nib = (x.x ? 1u : 0u) | (x.y ? 2u : 0u) | (x.z ? 4u : 0u) | (x.w ? 8u : 0u);
        word |= nib << (t * 4);
      }
    }
    ((unsigned int*)(ws + OFF_BITMAP))[(long long)R * WPR + w] = word;
  }
  int cnt = __popc(word);
  int usum = 0, umin = 0x7FFFFFFF, umax = -1;
  if (word) {
    umin = (w << 5) + __ffs(word) - 1;
    umax = (w << 5) + 31 - __clz(word);
    int bitsum = __popc(word & 0xAAAAAAAAu)
               + 2  * __popc(word & 0xCCCCCCCCu)
               + 4  * __popc(word & 0xF0F0F0F0u)
               + 8  * __popc(word & 0xFF00FF00u)
               + 16 * __popc(word & 0xFFFF0000u);
    usum = (w << 5) * cnt + bitsum;
  }
  for (int off = 32; off > 0; off >>= 1) {
    cnt  += __shfl_xor(cnt, off);
    usum += __shfl_xor(usum, off);
    umin = min(umin, __shfl_xor(umin, off));
    umax = max(umax, __shfl_xor(umax, off));
  }
  if (lane == 0) {
    ((int*)(ws + OFF_ROWCNT))[R] = cnt;
    ((int*)(ws + OFF_RUSUM))[R] = usum;
    ((int*)(ws + OFF_RUMIN))[R] = umin;
    ((int*)(ws + OFF_RUMAX))[R] = umax;
  }
}

// one block (4 waves) per mask: bbox+centroid+crop, bg row counts (LDS),
// fg/bg prefix scans, xyxy out. Fuses old k_bbox/k_bgcnt/k_scan.
__global__ __launch_bounds__(256) void k_mid(char* ws, float* out_xy) {
  __shared__ int s_cb[VMAX];
  __shared__ long long s_vs[4], s_us[4];
  __shared__ int s_cnt[4], s_v0[4], s_v1[4], s_u0[4], s_u1[4];
  __shared__ int s_crop[4];
  const int n = blockIdx.x;
  const int tid = threadIdx.x, wid = tid >> 6, lane = tid & 63;
  const int* rowcnt = (const int*)(ws + OFF_ROWCNT) + n * VMAX;
  const int* rusum  = (const int*)(ws + OFF_RUSUM)  + n * VMAX;
  const int* rumin  = (const int*)(ws + OFF_RUMIN)  + n * VMAX;
  const int* rumax  = (const int*)(ws + OFF_RUMAX)  + n * VMAX;

  // ---- phase 1: bbox + centroid (256-thread strided, wave partials) ----
  int cnt = 0, v0 = 0x7FFFFFFF, v1 = -1, u0 = 0x7FFFFFFF, u1 = -1;
  long long vsum = 0, usum = 0;
  for (int v = tid; v < VMAX; v += 256) {
    int c = rowcnt[v];
    if (c > 0) { v0 = min(v0, v); v1 = max(v1, v); u0 = min(u0, rumin[v]); u1 = max(u1, rumax[v]); }
    cnt += c; vsum += (long long)c * v; usum += (long long)rusum[v];
  }
  for (int off = 32; off > 0; off >>= 1) {
    cnt  += __shfl_xor(cnt, off);
    vsum += __shfl_xor(vsum, off);
    usum += __shfl_xor(usum, off);
    v0 = min(v0, __shfl_xor(v0, off));
    v1 = max(v1, __shfl_xor(v1, off));
    u0 = min(u0, __shfl_xor(u0, off));
    u1 = max(u1, __shfl_xor(u1, off));
  }
  if (lane == 0) {
    s_cnt[wid] = cnt; s_vs[wid] = vsum; s_us[wid] = usum;
    s_v0[wid] = v0; s_v1[wid] = v1; s_u0[wid] = u0; s_u1[wid] = u1;
  }
  __syncthreads();
  if (wid == 0) {
    int c2 = (lane < 4) ? s_cnt[lane] : 0;
    long long vs2 = (lane < 4) ? s_vs[lane] : 0, us2 = (lane < 4) ? s_us[lane] : 0;
    int a0 = (lane < 4) ? s_v0[lane] : 0x7FFFFFFF, a1 = (lane < 4) ? s_v1[lane] : -1;
    int b0 = (lane < 4) ? s_u0[lane] : 0x7FFFFFFF, b1 = (lane < 4) ? s_u1[lane] : -1;
    for (int off = 1; off <= 2; off <<= 1) {
      c2 += __shfl_xor(c2, off);
      vs2 += __shfl_xor(vs2, off);
      us2 += __shfl_xor(us2, off);
      a0 = min(a0, __shfl_xor(a0, off));
      a1 = max(a1, __shfl_xor(a1, off));
      b0 = min(b0, __shfl_xor(b0, off));
      b1 = max(b1, __shfl_xor(b1, off));
    }
    if (lane == 0) {
      int vlen = a1 + 1 - a0, ulen = b1 + 1 - b0;
      int dv = (int)floorf(0.2f * (float)vlen);      // replicate f32 floor exactly
      int du = (int)floorf(0.2f * (float)ulen);
      int v0e = max(0, a0 - dv), v1e = min(a1 + 1 + dv, VMAX - 1);
      int u0e = max(0, b0 - du), u1e = min(b1 + 1 + du, UMAX - 1);
      MaskInfo* info = (MaskInfo*)(ws + OFF_INFO) + n;
      info->v0e = v0e; info->v1e = v1e; info->u0e = u0e; info->u1e = u1e;
      info->cnt_fg = c2; info->cntf = (float)c2;
      info->vc = (float)((double)vs2 / (double)c2) - (float)v0e;
      info->uc = (float)((double)us2 / (double)c2) - (float)u0e;
      info->v0m = a0; info->v1m = a1;
      float* xy = out_xy + n * 4;
      xy[0] = (float)b0 / (float)UMAX; xy[1] = (float)a0 / (float)VMAX;
      xy[2] = (float)b1 / (float)UMAX; xy[3] = (float)a1 / (float)VMAX;
      s_crop[0] = v0e; s_crop[1] = v1e; s_crop[2] = u0e; s_crop[3] = u1e;
    }
  }
  __syncthreads();
  const int v0e = s_crop[0], v1e = s_crop[1], u0e = s_crop[2], u1e = s_crop[3];

  // ---- phase 2: bg per-row counts into LDS (wave per row, lane = word) ----
  const unsigned int* bmn = (const unsigned int*)(ws + OFF_BITMAP) + (long long)n * VMAX * WPR;
  for (int v = wid; v < VMAX; v += 4) {
    int cb = 0;
    if (v >= v0e && v < v1e && u1e > u0e) {   // wave-uniform branch
      unsigned int word = (lane < WPR) ? bmn[(long long)v * WPR + lane] : 0u;
      int c = __popc(word & rangemask(lane, u0e, u1e));
      for (int off = 32; off > 0; off >>= 1) c += __shfl_xor(c, off);
      cb = (u1e - u0e) - c;
    }
    if (lane == 0) s_cb[v] = cb;
  }
  __syncthreads();

  // ---- phase 3: fg scan (wave 0, from global rowcnt) + bg scan (wave 1, LDS) ----
  if (wid < 2) {
    const bool isF = (wid == 0);
    int* dst = (int*)(ws + (isF ? OFF_PF : OFF_PB)) + n * (VMAX + 1);
    int base = 0;
    for (int c = 0; c < VMAX; c += 64) {
      int v = c + lane;
      int s = 0;
      if (v < VMAX) s = isF ? rowcnt[v] : s_cb[v];
      for (int d = 1; d < 64; d <<= 1) { int t = __shfl_up(s, d); if (lane >= d) s += t; }
      if (v < VMAX) dst[v + 1] = base + s;
      base += __shfl(s, 63);
    }
    if (lane == 0) {
      dst[0] = 0;
      if (!isF) ((MaskInfo*)(ws + OFF_INFO))[n].cnt_bg = base;
    }
  }
}

// 512 blocks x 128 threads, 1 query/thread (32 blocks per mask)
__global__ __launch_bounds__(128) void k_sample(const float* __restrict__ img,
                                                const float* __restrict__ ufg,
                                                const float* __restrict__ ubg,
                                                const float* __restrict__ cat,
                                                char* ws, float* __restrict__ out) {
  __shared__ int s_p[VMAX + 1];
  __shared__ MaskInfo smi;
  const int gq = blockIdx.x * 128 + (int)threadIdx.x;  // 0..65535
  const int n = gq >> 12;            // /NPT
  const int qi = gq & (NPT - 1);     // 0..4095
  const bool isfg = qi < FGN;        // uniform per block (128 | 2048)
  const int* pp = (const int*)(ws + (isfg ? OFF_PF : OFF_PB)) + n * (VMAX + 1);
  for (int i = threadIdx.x; i <= VMAX; i += 128) s_p[i] = pp[i];
  if (threadIdx.x == 0) smi = ((const MaskInfo*)(ws + OFF_INFO))[n];
  __syncthreads();
  const unsigned int* bmall = (const unsigned int*)(ws + OFF_BITMAP);
  const unsigned int* bmn = bmall + (long long)n * VMAX * WPR;
  const int* rumin = (const int*)(ws + OFF_RUMIN) + n * VMAX;

  float r0 = 0, r1 = 0, r2 = 0, voff = 0, uoff = 0, o5 = 0, o6 = 0, o7 = 0;
  if (isfg) {
    float uf = ufg[n * FGN + qi];
    int rk = (int)(uf * smi.cntf);               // fp32 mul + trunc, matches ref
    int cm = smi.cnt_fg - 1; if (rk > cm) rk = cm;
    int lo = smi.v0m, hi = smi.v1m + 1;          // s_p[lo]=0<=rk<cnt=s_p[hi]
    while (hi - lo > 1) { int mid = (lo + hi) >> 1; if (s_p[mid] <= rk) lo = mid; else hi = mid; }
    int v = lo, rem = rk - s_p[v];
    const uint4* row4 = (const uint4*)(bmn + v * WPR);
    int w4 = rumin[v] >> 7;                      // start uint4 containing first set bit
    int u = 0;
    for (;; w4++) {
      uint4 x = row4[w4];
      int c0 = __popc(x.x), c1 = __popc(x.y), c2 = __popc(x.z), c3 = __popc(x.w);
      int t = c0 + c1 + c2 + c3;
      if (rem < t) {
        unsigned int word; int wi;
        if (rem < c0) { word = x.x; wi = 0; }
        else if (rem < c0 + c1) { word = x.y; wi = 1; rem -= c0; }
        else if (rem < c0 + c1 + c2) { word = x.z; wi = 2; rem -= c0 + c1; }
        else { word = x.w; wi = 3; rem -= c0 + c1 + c2; }
        while (rem--) word &= word - 1;
        u = ((w4 * 4 + wi) << 5) + __ffs(word) - 1;
        break;
      }
      rem -= t;
    }
    long long pos = (long long)v * UMAX + u;
    r0 = img[pos * 3]; r1 = img[pos * 3 + 1]; r2 = img[pos * 3 + 2];
    voff = ((float)v - (float)smi.v0e - smi.vc) * (1.0f / 128.0f);
    uoff = ((float)u - (float)smi.u0e - smi.uc) * (1.0f / 128.0f);
  } else if (smi.cnt_bg > 0) {
    int q = qi - FGN;
    float ub = ubg[n * BGN + q];
    int rk = (int)(ub * (float)smi.cnt_bg);
    int cm = smi.cnt_bg - 1; if (rk > cm) rk = cm;
    int lo = smi.v0e, hi = smi.v1e;              // pb[v0e]=0<=rk<cnt_bg=pb[v1e]
    while (hi - lo > 1) { int mid = (lo + hi) >> 1; if (s_p[mid] <= rk) lo = mid; else hi = mid; }
    int v = lo, rem = rk - s_p[v];
    const uint4* row4 = (const uint4*)(bmn + v * WPR);
    const int a = smi.u0e, b = smi.u1e;
    int u = 0;
    for (int w4 = a >> 7; ; w4++) {
      uint4 x = row4[w4];
      int base = w4 << 2;
      unsigned int b0 = (~x.x) & rangemask(base + 0, a, b);
      unsigned int b1 = (~x.y) & rangemask(base + 1, a, b);
      unsigned int b2 = (~x.z) & rangemask(base + 2, a, b);
      unsigned int b3 = (~x.w) & rangemask(base + 3, a, b);
      int c0 = __popc(b0), c1 = __popc(b1), c2 = __popc(b2), c3 = __popc(b3);
      int t = c0 + c1 + c2 + c3;
      if (rem < t) {
        unsigned int word; int wi;
        if (rem < c0) { word = b0; wi = 0; }
        else if (rem < c0 + c1) { word = b1; wi = 1; rem -= c0; }
        else if (rem < c0 + c1 + c2) { word = b2; wi = 2; rem -= c0 + c1; }
        else { word = b3; wi = 3; rem -= c0 + c1 + c2; }
        while (rem--) word &= word - 1;
        u = ((base + wi) << 5) + __ffs(word) - 1;
        break;
      }
      rem -= t;
    }
    long long pos = (long long)v * UMAX + u;
    r0 = img[pos * 3]; r1 = img[pos * 3 + 1]; r2 = img[pos * 3 + 2];
    voff = ((float)v - (float)smi.v0e - smi.vc) * (1.0f / 128.0f);
    uoff = ((float)u - (float)smi.u0e - smi.uc) * (1.0f / 128.0f);
    int uni = 0, wi = u >> 5, bi = u & 31;
    #pragma unroll
    for (int k2 = 0; k2 < NM; k2++)
      uni |= (int)((bmall[((long long)k2 * VMAX + v) * WPR + wi] >> bi) & 1u);
    const float* e = cat + (uni ? 6 : 0);
    o5 = e[0]; o6 = e[1]; o7 = e[2];
  }
  float* o = out + ((long long)(n * NPT + qi)) * 8;
  o[0] = r0; o[1] = r1; o[2] = r2; o[3] = voff; o[4] = uoff; o[5] = o5; o[6] = o6; o[7] = o7;
}

extern "C" void kernel_launch(void* const* d_in, const int* in_sizes, int n_in,
                              void* d_out, int out_size, void* d_ws, size_t ws_size,
                              hipStream_t stream) {
  const float* img  = (const float*)d_in[0];
  const void*  masks = d_in[1];
  const float* ufg  = (const float*)d_in[2];
  const float* ubg  = (const float*)d_in[3];
  const float* cat  = (const float*)d_in[4];
  float* out = (float*)d_out;
  char* ws = (char*)d_ws;

  hipLaunchKernelGGL(k_detect, dim3(DET_BLOCKS), dim3(256), 0, stream,
                     (const uint4*)masks, (int*)(ws + OFF_FLAG));
  hipLaunchKernelGGL(k_rows, dim3(NM * VMAX / 4), dim3(256), 0, stream, masks, ws);
  hipLaunchKernelGGL(k_mid, dim3(NM), dim3(256), 0, stream, ws, out + PTS_FLOATS);
  hipLaunchKernelGGL(k_sample, dim3(NM * NPT / 128), dim3(128), 0, stream,
                     img, ufg, ubg, cat, ws, out);
}

// Round 7
// 63.647 us; speedup vs baseline: 2.0140x; 2.0140x over previous
//
#include <hip/hip_runtime.h>
#include <math.h>

#define NM 16
#define VMAX 1080
#define UMAX 1920
#define WPR (UMAX/32)          // 60 words per row (240 B, 16B-aligned)
#define FGN 2048
#define BGN 2048
#define NPT (FGN+BGN)          // 4096
#define PTS_FLOATS (NM*NPT*8)  // 524288
#define DET_BLOCKS 64
#define DET_WORDS (VMAX*UMAX/4)   // scan mask 0 as-if-u8: 518400 words (2 MB)

// ---- workspace layout (bytes) ----
#define OFF_FLAG    0              // 64 ints: per-detect-block dtype code
#define OFF_INFO    256
#define OFF_BITMAP  4096
#define OFF_ROWCNT  (OFF_BITMAP + NM*VMAX*WPR*4)
#define OFF_RUSUM   (OFF_ROWCNT + NM*VMAX*4)
#define OFF_RUMIN   (OFF_RUSUM  + NM*VMAX*4)
#define OFF_RUMAX   (OFF_RUMIN  + NM*VMAX*4)
#define OFF_PF      (OFF_RUMAX  + NM*VMAX*4)
#define OFF_PB      (OFF_PF     + NM*(VMAX+1)*4)
// end ~4.5 MB

struct MaskInfo {
  int v0e, v1e, u0e, u1e, cnt_fg, cnt_bg;
  float cntf, vc, uc;
  int v0m, v1m;
  int pad[5];
};

// bits of word index widx that fall in bit-range [a, b)
__device__ inline unsigned int rangemask(int widx, int a, int b) {
  int lo = widx << 5, hi = lo + 32;
  if (b <= lo || a >= hi) return 0u;
  unsigned int m = 0xFFFFFFFFu;
  if (a > lo) m &= 0xFFFFFFFFu << (a - lo);
  if (b < hi) m &= (1u << (b - lo)) - 1u;
  return m;
}

// u8-evidence: any byte above byte0 nonzero, and the word cannot be a lone
// f32 1.0f. (u8 masks of 0/1 bytes can never form 0x3F800000.)
__device__ inline int u8_evidence(unsigned int x) {
  return (x & 0xFFFFFF00u) != 0u && x != 0x3F800000u;
}

// 64 blocks; block b scans its strided share of mask 0 (as-if-u8 = 2MB) and
// plain-stores code to flag[b]: 2 = u8 evidence, 3 = none. No atomics, no
// zero-init needed; deterministic regardless of prior flag contents.
__global__ __launch_bounds__(256) void k_detect(const uint4* w4, int* flag) {
  __shared__ int sev;
  if (threadIdx.x == 0) sev = 0;
  __syncthreads();
  int local = 0;
  const int nq = DET_WORDS / 4;  // 129600 uint4s
  for (int i = blockIdx.x * 256 + threadIdx.x; i < nq; i += DET_BLOCKS * 256) {
    uint4 x = w4[i];
    local |= u8_evidence(x.x) | u8_evidence(x.y) | u8_evidence(x.z) | u8_evidence(x.w);
  }
  if (__any(local)) { if ((threadIdx.x & 63) == 0) atomicOr(&sev, 1); }
  __syncthreads();
  if (threadIdx.x == 0) flag[blockIdx.x] = sev ? 2 : 3;
}

__device__ inline unsigned int bits4(unsigned int x) {  // 4 bytes -> 4 bits
  unsigned int r = 0;
  r |= (x & 0x000000FFu) ? 1u : 0u;
  r |= (x & 0x0000FF00u) ? 2u : 0u;
  r |= (x & 0x00FF0000u) ? 4u : 0u;
  r |= (x & 0xFF000000u) ? 8u : 0u;
  return r;
}
__device__ inline unsigned int bits16(uint4 q) {        // 16 bytes -> 16 bits
  return bits4(q.x) | (bits4(q.y) << 4) | (bits4(q.z) << 8) | (bits4(q.w) << 12);
}

// 4 waves per block, one wave per (mask,row); lane w owns bitmap word w
__global__ __launch_bounds__(256) void k_rows(const void* masks, char* ws) {
  const int R = blockIdx.x * 4 + (threadIdx.x >> 6);  // global row 0..NM*VMAX-1
  const int lane = threadIdx.x & 63;
  const int n = R / VMAX, v = R % VMAX;
  // mode: wave-reduce min over the 64 detect codes (one coalesced load)
  int code = ((const int*)(ws + OFF_FLAG))[lane];
  for (int off = 32; off > 0; off >>= 1) code = min(code, __shfl_xor(code, off));
  const bool is_u8 = (code == 2);
  const long long base = (long long)n * VMAX * UMAX + (long long)v * UMAX;  // element idx
  const int w = lane;
  unsigned int word = 0;
  if (w < WPR) {
    if (is_u8) {                // u8: 32 bytes = 2 x uint4
      const uint4* p = (const uint4*)((const unsigned char*)masks + base) + w * 2;
      uint4 a = p[0], b = p[1];
      word = bits16(a) | (bits16(b) << 16);
    } else {                    // i32 / f32: 32 dwords = 8 x uint4, nonzero == true
      const uint4* p = (const uint4*)((const unsigned int*)masks + base) + w * 8;
      #pragma unroll
      for (int t = 0; t < 8; t++) {
        uint4 x = p[t];
        unsigned int nib = (x.x ? 1u : 0u) | (x.y ? 2u : 0u) | (x.z ? 4u : 0u) | (x.w ? 8u : 0u);
        word |= nib << (t * 4);
      }
    }
    ((unsigned int*)(ws + OFF_BITMAP))[(long long)R * WPR + w] = word;
  }
  int cnt = __popc(word);
  int usum = 0, umin = 0x7FFFFFFF, umax = -1;
  if (word) {
    umin = (w << 5) + __ffs(word) - 1;
    umax = (w << 5) + 31 - __clz(word);
    int bitsum = __popc(word & 0xAAAAAAAAu)
               + 2  * __popc(word & 0xCCCCCCCCu)
               + 4  * __popc(word & 0xF0F0F0F0u)
               + 8  * __popc(word & 0xFF00FF00u)
               + 16 * __popc(word & 0xFFFF0000u);
    usum = (w << 5) * cnt + bitsum;
  }
  for (int off = 32; off > 0; off >>= 1) {
    cnt  += __shfl_xor(cnt, off);
    usum += __shfl_xor(usum, off);
    umin = min(umin, __shfl_xor(umin, off));
    umax = max(umax, __shfl_xor(umax, off));
  }
  if (lane == 0) {
    ((int*)(ws + OFF_ROWCNT))[R] = cnt;
    ((int*)(ws + OFF_RUSUM))[R] = usum;
    ((int*)(ws + OFF_RUMIN))[R] = umin;
    ((int*)(ws + OFF_RUMAX))[R] = umax;
  }
}

// one block (16 waves, 1024 thr) per mask:
//  phase1: bbox+centroid+crop (block reduction)
//  phase2: wave0 = fg prefix scan; waves1-15 = thread-per-row bg counts -> LDS
//  phase3: wave1 = bg prefix scan from LDS
__global__ __launch_bounds__(1024) void k_prep(char* ws, float* out_xy) {
  __shared__ int s_cb[VMAX];
  __shared__ long long s_vs[16], s_us[16];
  __shared__ int s_cnt[16], s_v0[16], s_v1[16], s_u0[16], s_u1[16];
  __shared__ int s_crop[4];
  const int n = blockIdx.x;
  const int tid = threadIdx.x, wid = tid >> 6, lane = tid & 63;
  const int* rowcnt = (const int*)(ws + OFF_ROWCNT) + n * VMAX;
  const int* rusum  = (const int*)(ws + OFF_RUSUM)  + n * VMAX;
  const int* rumin  = (const int*)(ws + OFF_RUMIN)  + n * VMAX;
  const int* rumax  = (const int*)(ws + OFF_RUMAX)  + n * VMAX;

  // ---- phase 1: bbox + centroid ----
  int cnt = 0, v0 = 0x7FFFFFFF, v1 = -1, u0 = 0x7FFFFFFF, u1 = -1;
  long long vsum = 0, usum = 0;
  for (int v = tid; v < VMAX; v += 1024) {
    int c = rowcnt[v];
    if (c > 0) { v0 = min(v0, v); v1 = max(v1, v); u0 = min(u0, rumin[v]); u1 = max(u1, rumax[v]); }
    cnt += c; vsum += (long long)c * v; usum += (long long)rusum[v];
  }
  for (int off = 32; off > 0; off >>= 1) {
    cnt  += __shfl_xor(cnt, off);
    vsum += __shfl_xor(vsum, off);
    usum += __shfl_xor(usum, off);
    v0 = min(v0, __shfl_xor(v0, off));
    v1 = max(v1, __shfl_xor(v1, off));
    u0 = min(u0, __shfl_xor(u0, off));
    u1 = max(u1, __shfl_xor(u1, off));
  }
  if (lane == 0) {
    s_cnt[wid] = cnt; s_vs[wid] = vsum; s_us[wid] = usum;
    s_v0[wid] = v0; s_v1[wid] = v1; s_u0[wid] = u0; s_u1[wid] = u1;
  }
  __syncthreads();
  if (wid == 0) {
    int c2 = (lane < 16) ? s_cnt[lane] : 0;
    long long vs2 = (lane < 16) ? s_vs[lane] : 0, us2 = (lane < 16) ? s_us[lane] : 0;
    int a0 = (lane < 16) ? s_v0[lane] : 0x7FFFFFFF, a1 = (lane < 16) ? s_v1[lane] : -1;
    int b0 = (lane < 16) ? s_u0[lane] : 0x7FFFFFFF, b1 = (lane < 16) ? s_u1[lane] : -1;
    for (int off = 1; off <= 8; off <<= 1) {
      c2 += __shfl_xor(c2, off);
      vs2 += __shfl_xor(vs2, off);
      us2 += __shfl_xor(us2, off);
      a0 = min(a0, __shfl_xor(a0, off));
      a1 = max(a1, __shfl_xor(a1, off));
      b0 = min(b0, __shfl_xor(b0, off));
      b1 = max(b1, __shfl_xor(b1, off));
    }
    if (lane == 0) {
      int vlen = a1 + 1 - a0, ulen = b1 + 1 - b0;
      int dv = (int)floorf(0.2f * (float)vlen);      // replicate f32 floor exactly
      int du = (int)floorf(0.2f * (float)ulen);
      int v0e = max(0, a0 - dv), v1e = min(a1 + 1 + dv, VMAX - 1);
      int u0e = max(0, b0 - du), u1e = min(b1 + 1 + du, UMAX - 1);
      MaskInfo* info = (MaskInfo*)(ws + OFF_INFO) + n;
      info->v0e = v0e; info->v1e = v1e; info->u0e = u0e; info->u1e = u1e;
      info->cnt_fg = c2; info->cntf = (float)c2;
      info->vc = (float)((double)vs2 / (double)c2) - (float)v0e;
      info->uc = (float)((double)us2 / (double)c2) - (float)u0e;
      info->v0m = a0; info->v1m = a1;
      float* xy = out_xy + n * 4;
      xy[0] = (float)b0 / (float)UMAX; xy[1] = (float)a0 / (float)VMAX;
      xy[2] = (float)b1 / (float)UMAX; xy[3] = (float)a1 / (float)VMAX;
      s_crop[0] = v0e; s_crop[1] = v1e; s_crop[2] = u0e; s_crop[3] = u1e;
    }
  }
  __syncthreads();
  const int v0e = s_crop[0], v1e = s_crop[1], u0e = s_crop[2], u1e = s_crop[3];
  const unsigned int* bmn = (const unsigned int*)(ws + OFF_BITMAP) + (long long)n * VMAX * WPR;

  // ---- phase 2: wave0 fg-scan ; waves 1..15 thread-per-row bg counts ----
  if (wid == 0) {
    int* pf = (int*)(ws + OFF_PF) + n * (VMAX + 1);
    int base = 0;
    for (int c = 0; c < VMAX; c += 64) {
      int v = c + lane;
      int s = (v < VMAX) ? rowcnt[v] : 0;
      for (int d = 1; d < 64; d <<= 1) { int t = __shfl_up(s, d); if (lane >= d) s += t; }
      if (v < VMAX) pf[v + 1] = base + s;
      base += __shfl(s, 63);
    }
    if (lane == 0) pf[0] = 0;
  } else {
    for (int v = tid - 64; v < VMAX; v += 960) {
      int cb = 0;
      if (v >= v0e && v < v1e && u1e > u0e) {
        int wlo = u0e >> 5, whi = (u1e - 1) >> 5, c = 0;
        const unsigned int* row = bmn + (long long)v * WPR;
        for (int w = wlo; w <= whi; w++) c += __popc(row[w] & rangemask(w, u0e, u1e));
        cb = (u1e - u0e) - c;
      }
      s_cb[v] = cb;
    }
  }
  __syncthreads();

  // ---- phase 3: wave 1 bg-scan from LDS ----
  if (wid == 1) {
    int* pb = (int*)(ws + OFF_PB) + n * (VMAX + 1);
    int base = 0;
    for (int c = 0; c < VMAX; c += 64) {
      int v = c + lane;
      int s = (v < VMAX) ? s_cb[v] : 0;
      for (int d = 1; d < 64; d <<= 1) { int t = __shfl_up(s, d); if (lane >= d) s += t; }
      if (v < VMAX) pb[v + 1] = base + s;
      base += __shfl(s, 63);
    }
    if (lane == 0) {
      pb[0] = 0;
      ((MaskInfo*)(ws + OFF_INFO))[n].cnt_bg = base;
    }
  }
}

// 512 blocks x 128 threads, 1 query/thread (32 blocks per mask)
__global__ __launch_bounds__(128) void k_sample(const float* __restrict__ img,
                                                const float* __restrict__ ufg,
                                                const float* __restrict__ ubg,
                                                const float* __restrict__ cat,
                                                char* ws, float* __restrict__ out) {
  __shared__ int s_p[VMAX + 1];
  __shared__ MaskInfo smi;
  const int gq = blockIdx.x * 128 + (int)threadIdx.x;  // 0..65535
  const int n = gq >> 12;            // /NPT
  const int qi = gq & (NPT - 1);     // 0..4095
  const bool isfg = qi < FGN;        // uniform per block (128 | 2048)
  const int* pp = (const int*)(ws + (isfg ? OFF_PF : OFF_PB)) + n * (VMAX + 1);
  for (int i = threadIdx.x; i <= VMAX; i += 128) s_p[i] = pp[i];
  if (threadIdx.x == 0) smi = ((const MaskInfo*)(ws + OFF_INFO))[n];
  __syncthreads();
  const unsigned int* bmall = (const unsigned int*)(ws + OFF_BITMAP);
  const unsigned int* bmn = bmall + (long long)n * VMAX * WPR;
  const int* rumin = (const int*)(ws + OFF_RUMIN) + n * VMAX;

  float r0 = 0, r1 = 0, r2 = 0, voff = 0, uoff = 0, o5 = 0, o6 = 0, o7 = 0;
  if (isfg) {
    float uf = ufg[n * FGN + qi];
    int rk = (int)(uf * smi.cntf);               // fp32 mul + trunc, matches ref
    int cm = smi.cnt_fg - 1; if (rk > cm) rk = cm;
    int lo = smi.v0m, hi = smi.v1m + 1;          // s_p[lo]=0<=rk<cnt=s_p[hi]
    while (hi - lo > 1) { int mid = (lo + hi) >> 1; if (s_p[mid] <= rk) lo = mid; else hi = mid; }
    int v = lo, rem = rk - s_p[v];
    const uint4* row4 = (const uint4*)(bmn + v * WPR);
    int w4 = rumin[v] >> 7;                      // start uint4 containing first set bit
    int u = 0;
    for (;; w4++) {
      uint4 x = row4[w4];
      int c0 = __popc(x.x), c1 = __popc(x.y), c2 = __popc(x.z), c3 = __popc(x.w);
      int t = c0 + c1 + c2 + c3;
      if (rem < t) {
        unsigned int word; int wi;
        if (rem < c0) { word = x.x; wi = 0; }
        else if (rem < c0 + c1) { word = x.y; wi = 1; rem -= c0; }
        else if (rem < c0 + c1 + c2) { word = x.z; wi = 2; rem -= c0 + c1; }
        else { word = x.w; wi = 3; rem -= c0 + c1 + c2; }
        while (rem--) word &= word - 1;
        u = ((w4 * 4 + wi) << 5) + __ffs(word) - 1;
        break;
      }
      rem -= t;
    }
    long long pos = (long long)v * UMAX + u;
    r0 = img[pos * 3]; r1 = img[pos * 3 + 1]; r2 = img[pos * 3 + 2];
    voff = ((float)v - (float)smi.v0e - smi.vc) * (1.0f / 128.0f);
    uoff = ((float)u - (float)smi.u0e - smi.uc) * (1.0f / 128.0f);
  } else if (smi.cnt_bg > 0) {
    int q = qi - FGN;
    float ub = ubg[n * BGN + q];
    int rk = (int)(ub * (float)smi.cnt_bg);
    int cm = smi.cnt_bg - 1; if (rk > cm) rk = cm;
    int lo = smi.v0e, hi = smi.v1e;              // pb[v0e]=0<=rk<cnt_bg=pb[v1e]
    while (hi - lo > 1) { int mid = (lo + hi) >> 1; if (s_p[mid] <= rk) lo = mid; else hi = mid; }
    int v = lo, rem = rk - s_p[v];
    const uint4* row4 = (const uint4*)(bmn + v * WPR);
    const int a = smi.u0e, b = smi.u1e;
    int u = 0;
    for (int w4 = a >> 7; ; w4++) {
      uint4 x = row4[w4];
      int base = w4 << 2;
      unsigned int b0 = (~x.x) & rangemask(base + 0, a, b);
      unsigned int b1 = (~x.y) & rangemask(base + 1, a, b);
      unsigned int b2 = (~x.z) & rangemask(base + 2, a, b);
      unsigned int b3 = (~x.w) & rangemask(base + 3, a, b);
      int c0 = __popc(b0), c1 = __popc(b1), c2 = __popc(b2), c3 = __popc(b3);
      int t = c0 + c1 + c2 + c3;
      if (rem < t) {
        unsigned int word; int wi;
        if (rem < c0) { word = b0; wi = 0; }
        else if (rem < c0 + c1) { word = b1; wi = 1; rem -= c0; }
        else if (rem < c0 + c1 + c2) { word = b2; wi = 2; rem -= c0 + c1; }
        else { word = b3; wi = 3; rem -= c0 + c1 + c2; }
        while (rem--) word &= word - 1;
        u = ((base + wi) << 5) + __ffs(word) - 1;
        break;
      }
      rem -= t;
    }
    long long pos = (long long)v * UMAX + u;
    r0 = img[pos * 3]; r1 = img[pos * 3 + 1]; r2 = img[pos * 3 + 2];
    voff = ((float)v - (float)smi.v0e - smi.vc) * (1.0f / 128.0f);
    uoff = ((float)u - (float)smi.u0e - smi.uc) * (1.0f / 128.0f);
    int uni = 0, wi = u >> 5, bi = u & 31;
    #pragma unroll
    for (int k2 = 0; k2 < NM; k2++)
      uni |= (int)((bmall[((long long)k2 * VMAX + v) * WPR + wi] >> bi) & 1u);
    const float* e = cat + (uni ? 6 : 0);
    o5 = e[0]; o6 = e[1]; o7 = e[2];
  }
  float* o = out + ((long long)(n * NPT + qi)) * 8;
  o[0] = r0; o[1] = r1; o[2] = r2; o[3] = voff; o[4] = uoff; o[5] = o5; o[6] = o6; o[7] = o7;
}

extern "C" void kernel_launch(void* const* d_in, const int* in_sizes, int n_in,
                              void* d_out, int out_size, void* d_ws, size_t ws_size,
                              hipStream_t stream) {
  const float* img  = (const float*)d_in[0];
  const void*  masks = d_in[1];
  const float* ufg  = (const float*)d_in[2];
  const float* ubg  = (const float*)d_in[3];
  const float* cat  = (const float*)d_in[4];
  float* out = (float*)d_out;
  char* ws = (char*)d_ws;

  hipLaunchKernelGGL(k_detect, dim3(DET_BLOCKS), dim3(256), 0, stream,
                     (const uint4*)masks, (int*)(ws + OFF_FLAG));
  hipLaunchKernelGGL(k_rows, dim3(NM * VMAX / 4), dim3(256), 0, stream, masks, ws);
  hipLaunchKernelGGL(k_prep, dim3(NM), dim3(1024), 0, stream, ws, out + PTS_FLOATS);
  hipLaunchKernelGGL(k_sample, dim3(NM * NPT / 128), dim3(128), 0, stream,
                     img, ufg, ubg, cat, ws, out);
}